// Round 6
// baseline (254.782 us; speedup 1.0000x reference)
//
#include <hip/hip_runtime.h>
#include <hip/hip_bf16.h>
#include <math.h>

#define L 2048
#define D 256
#define NEG_FLT_MAX (-3.402823466e38f)

typedef __attribute__((ext_vector_type(8))) short bf16x8;
typedef __attribute__((ext_vector_type(4))) float f32x4;
typedef __attribute__((ext_vector_type(4))) int i32x4;

__device__ __forceinline__ unsigned short f2bf(float f) {
    union { float f; unsigned int u; } v; v.f = f;
    unsigned int r = v.u + 0x7FFFu + ((v.u >> 16) & 1u);   // RNE
    return (unsigned short)(r >> 16);
}

// Barrier that drains ONLY LDS ops (lgkmcnt), leaving global loads in
// flight across it. __syncthreads() would emit s_waitcnt vmcnt(0) and
// drain the register prefetches -> full load latency exposed every iter
// (the documented pre-barrier drain). Memory-clobber asms pin ordering:
// ds_write can't sink below, ds_read can't hoist above.
__device__ __forceinline__ void wg_barrier_lds() {
    asm volatile("s_waitcnt lgkmcnt(0)" ::: "memory");
    __builtin_amdgcn_s_barrier();
    asm volatile("" ::: "memory");
}

// --- prep: fused {Wv transpose -> LDS} + {value @ Wv + bv -> Vt bf16}
//     + side-job {Wo transpose -> Wot global}
// 32x64 tile, grid (256,4) = 1024 blocks -> 4 blocks/CU
__global__ __launch_bounds__(256, 4) void prep_kernel(
    const float* __restrict__ value, const float* __restrict__ Wv,
    const float* __restrict__ bv, const float* __restrict__ Wo,
    unsigned short* __restrict__ Vt, unsigned short* __restrict__ Wot) {
    const int tid = threadIdx.x;
    const int wave = tid >> 6, lane = tid & 63;
    const int lm = lane & 15, q = lane >> 4;
    const int rh = wave >> 1;          // row half (16 rows each)
    const int nh = wave & 1;           // n half (32 cols each)
    const int m0 = blockIdx.x * 32;
    const int n0 = blockIdx.y * 64;

    __shared__ __align__(16) unsigned short Wlds[64][264];   // [n-local][k] bf16

    // side job: Wo transpose (64 elements per block, 1024 blocks cover 64K)
    {
        int bid = blockIdx.y * 256 + blockIdx.x;
        if (tid < 64) {
            int e = bid * 64 + tid;
            int k = e >> 8, n = e & 255;
            Wot[n * 256 + k] = f2bf(Wo[k * 256 + n]);
        }
    }

    // stage Wv[0:256][n0:n0+64] -> Wlds[n][k], coalesced f32 reads
    {
        int krow = tid >> 4;           // 0..15
        int nrel = (tid & 15) * 4;     // 0..60
#pragma unroll
        for (int p = 0; p < 16; p++) {
            int k = p * 16 + krow;
            f32x4 w = *reinterpret_cast<const f32x4*>(Wv + (size_t)k * 256 + n0 + nrel);
            Wlds[nrel + 0][k] = f2bf(w[0]);
            Wlds[nrel + 1][k] = f2bf(w[1]);
            Wlds[nrel + 2][k] = f2bf(w[2]);
            Wlds[nrel + 3][k] = f2bf(w[3]);
        }
    }
    __syncthreads();

    const int nl0 = nh * 32 + lm;          // local n, fragment 0
    const int nl1 = nh * 32 + 16 + lm;     // local n, fragment 1
    const int arow = m0 + rh * 16 + lm;

    f32x4 acc[2];
    acc[0] = (f32x4)(0.f); acc[1] = (f32x4)(0.f);

    const float* ap = value + (size_t)arow * 256;
    f32x4 pa0 = *reinterpret_cast<const f32x4*>(ap + q * 8);
    f32x4 pa1 = *reinterpret_cast<const f32x4*>(ap + q * 8 + 4);

    for (int k0 = 0; k0 < 256; k0 += 32) {
        f32x4 a0 = pa0, a1 = pa1;
        if (k0 < 224) {
            int kq = k0 + 32 + q * 8;
            pa0 = *reinterpret_cast<const f32x4*>(ap + kq);
            pa1 = *reinterpret_cast<const f32x4*>(ap + kq + 4);
        }
        bf16x8 b0 = *reinterpret_cast<const bf16x8*>(&Wlds[nl0][k0 + q * 8]);
        bf16x8 b1 = *reinterpret_cast<const bf16x8*>(&Wlds[nl1][k0 + q * 8]);
        bf16x8 afr;
#pragma unroll
        for (int e = 0; e < 4; e++) afr[e] = (short)f2bf(a0[e]);
#pragma unroll
        for (int e = 0; e < 4; e++) afr[4 + e] = (short)f2bf(a1[e]);
        acc[0] = __builtin_amdgcn_mfma_f32_16x16x32_bf16(afr, b0, acc[0], 0, 0, 0);
        acc[1] = __builtin_amdgcn_mfma_f32_16x16x32_bf16(afr, b1, acc[1], 0, 0, 0);
    }

    int mrow = m0 + rh * 16 + q * 4;       // rows mrow..mrow+3
    int b = mrow >> 11;
    int j = mrow & 2047;
#pragma unroll
    for (int nf = 0; nf < 2; nf++) {
        int n = n0 + nh * 32 + nf * 16 + lm;
        float bias_n = bv[n];
        const f32x4& a = acc[nf];
        unsigned short* dst = Vt + (size_t)b * (D * L) + (size_t)n * L + j;
        ushort4 pk;
        pk.x = f2bf(a[0] + bias_n);
        pk.y = f2bf(a[1] + bias_n);
        pk.z = f2bf(a[2] + bias_n);
        pk.w = f2bf(a[3] + bias_n);
        *reinterpret_cast<ushort4*>(dst) = pk;
    }
}

// --- fused mask + no-max softmax + P@V + /l + @Wo + bo -> out -----------
// r5 skeleton; single change this round: in-loop barriers keep global
// prefetches IN FLIGHT (wg_barrier_lds drains lgkmcnt only), so the
// double-buffered next-tile loads finally overlap a full iteration.
// + s_setprio(1) around the MFMA cluster (blocks run desynchronized).
__global__ __launch_bounds__(256, 2) void attn_kernel(
    const float* __restrict__ atten, const float* __restrict__ mask,
    const int* __restrict__ pad, const unsigned short* __restrict__ Vt,
    const unsigned short* __restrict__ Wot, const float* __restrict__ bo,
    float* __restrict__ out) {
    const int bid = blockIdx.x;        // 0..511
    const int g = (bid & 7) * 64 + (bid >> 3);   // XCD-chunked: XCD pair -> one batch
    const int b = g >> 7;
    const int i0 = (g & 127) * 16;
    const int tid = threadIdx.x;
    const int wave = tid >> 6, lane = tid & 63;
    const int lm = lane & 15, q = lane >> 4;
    const int r = tid >> 4;            // softmax row 0..15
    const int c = (tid & 15) * 8;      // j offset within 128-tile

    __shared__ __align__(16) unsigned short Plds[2][16][136];
    __shared__ __align__(16) unsigned short A_lds[16][264];
    __shared__ float l_lds[16];

    f32x4 acc[4];
#pragma unroll
    for (int nf = 0; nf < 4; nf++) acc[nf] = (f32x4)(0.f);
    float lsum = 0.f;

    const size_t rowoff = ((size_t)(b * L + i0 + r)) * L + c;
    const float* at_p = atten + rowoff;
    const float* mk_p = mask + rowoff;
    const int*   pd_p = pad + rowoff;
    const unsigned short* vt_b = Vt + (size_t)b * (D * L) + q * 8;

    // double-buffered register state: tile logits + Vt fragments
    f32x4 laA0, laA1, lmA0, lmA1, laB0, laB1, lmB0, lmB1;
    i32x4 lpA0, lpA1, lpB0, lpB1;
    bf16x8 bfrA[4][4], bfrB[4][4];

    // prefetch tile 0 into A
    laA0 = *reinterpret_cast<const f32x4*>(at_p);
    laA1 = *reinterpret_cast<const f32x4*>(at_p + 4);
    lmA0 = *reinterpret_cast<const f32x4*>(mk_p);
    lmA1 = *reinterpret_cast<const f32x4*>(mk_p + 4);
    lpA0 = *reinterpret_cast<const i32x4*>(pd_p);
    lpA1 = *reinterpret_cast<const i32x4*>(pd_p + 4);
#pragma unroll
    for (int kk = 0; kk < 4; kk++)
#pragma unroll
        for (int nf = 0; nf < 4; nf++) {
            int n = wave * 64 + nf * 16 + lm;
            bfrA[kk][nf] = *reinterpret_cast<const bf16x8*>(
                vt_b + (size_t)n * L + kk * 32);
        }

    for (int jt = 0; jt < 16; jt += 2) {
        // ================= even tile: consume A, prefetch B ==============
        {
            const int j0 = jt * 128;
            bf16x8 pk;
#pragma unroll
            for (int e = 0; e < 4; e++) {
                float sv = (lmA0[e] < 0.5f) ? NEG_FLT_MAX : laA0[e];
                sv = (lpA0[e] == 0) ? -INFINITY : sv;
                float pv = __expf(sv);
                lsum += pv;
                pk[e] = (short)f2bf(pv);
                float sw = (lmA1[e] < 0.5f) ? NEG_FLT_MAX : laA1[e];
                sw = (lpA1[e] == 0) ? -INFINITY : sw;
                float pw = __expf(sw);
                lsum += pw;
                pk[4 + e] = (short)f2bf(pw);
            }
            *reinterpret_cast<bf16x8*>(&Plds[0][r][c]) = pk;
            // prefetch tile jt+1 into B (stays in flight across the barrier)
            {
                const int jn = j0 + 128;
                laB0 = *reinterpret_cast<const f32x4*>(at_p + jn);
                laB1 = *reinterpret_cast<const f32x4*>(at_p + jn + 4);
                lmB0 = *reinterpret_cast<const f32x4*>(mk_p + jn);
                lmB1 = *reinterpret_cast<const f32x4*>(mk_p + jn + 4);
                lpB0 = *reinterpret_cast<const i32x4*>(pd_p + jn);
                lpB1 = *reinterpret_cast<const i32x4*>(pd_p + jn + 4);
#pragma unroll
                for (int kk = 0; kk < 4; kk++)
#pragma unroll
                    for (int nf = 0; nf < 4; nf++) {
                        int n = wave * 64 + nf * 16 + lm;
                        bfrB[kk][nf] = *reinterpret_cast<const bf16x8*>(
                            vt_b + (size_t)n * L + jn + kk * 32);
                    }
            }
            wg_barrier_lds();
            __builtin_amdgcn_s_setprio(1);
#pragma unroll
            for (int kk = 0; kk < 4; kk++) {
                bf16x8 afr = *reinterpret_cast<const bf16x8*>(
                    &Plds[0][lm][kk * 32 + q * 8]);
#pragma unroll
                for (int nf = 0; nf < 4; nf++)
                    acc[nf] = __builtin_amdgcn_mfma_f32_16x16x32_bf16(
                        afr, bfrA[kk][nf], acc[nf], 0, 0, 0);
            }
            __builtin_amdgcn_s_setprio(0);
        }
        // ================= odd tile: consume B, prefetch A ===============
        {
            const int j0 = jt * 128 + 128;
            bf16x8 pk;
#pragma unroll
            for (int e = 0; e < 4; e++) {
                float sv = (lmB0[e] < 0.5f) ? NEG_FLT_MAX : laB0[e];
                sv = (lpB0[e] == 0) ? -INFINITY : sv;
                float pv = __expf(sv);
                lsum += pv;
                pk[e] = (short)f2bf(pv);
                float sw = (lmB1[e] < 0.5f) ? NEG_FLT_MAX : laB1[e];
                sw = (lpB1[e] == 0) ? -INFINITY : sw;
                float pw = __expf(sw);
                lsum += pw;
                pk[4 + e] = (short)f2bf(pw);
            }
            *reinterpret_cast<bf16x8*>(&Plds[1][r][c]) = pk;
            if (jt < 14) {             // prefetch tile jt+2 into A
                const int jn = j0 + 128;
                laA0 = *reinterpret_cast<const f32x4*>(at_p + jn);
                laA1 = *reinterpret_cast<const f32x4*>(at_p + jn + 4);
                lmA0 = *reinterpret_cast<const f32x4*>(mk_p + jn);
                lmA1 = *reinterpret_cast<const f32x4*>(mk_p + jn + 4);
                lpA0 = *reinterpret_cast<const i32x4*>(pd_p + jn);
                lpA1 = *reinterpret_cast<const i32x4*>(pd_p + jn + 4);
#pragma unroll
                for (int kk = 0; kk < 4; kk++)
#pragma unroll
                    for (int nf = 0; nf < 4; nf++) {
                        int n = wave * 64 + nf * 16 + lm;
                        bfrA[kk][nf] = *reinterpret_cast<const bf16x8*>(
                            vt_b + (size_t)n * L + jn + kk * 32);
                    }
            }
            wg_barrier_lds();
            __builtin_amdgcn_s_setprio(1);
#pragma unroll
            for (int kk = 0; kk < 4; kk++) {
                bf16x8 afr = *reinterpret_cast<const bf16x8*>(
                    &Plds[1][lm][kk * 32 + q * 8]);
#pragma unroll
                for (int nf = 0; nf < 4; nf++)
                    acc[nf] = __builtin_amdgcn_mfma_f32_16x16x32_bf16(
                        afr, bfrB[kk][nf], acc[nf], 0, 0, 0);
            }
            __builtin_amdgcn_s_setprio(0);
        }
    }

    // deferred l-reduction: 16 threads (consecutive tids) share row r
    lsum += __shfl_xor(lsum, 1);
    lsum += __shfl_xor(lsum, 2);
    lsum += __shfl_xor(lsum, 4);
    lsum += __shfl_xor(lsum, 8);
    if ((tid & 15) == 0) l_lds[r] = lsum;
    __syncthreads();

    // normalize, pack bf16 A for the out-projection
    float linv[4];
#pragma unroll
    for (int rg = 0; rg < 4; rg++) linv[rg] = 1.f / l_lds[q * 4 + rg];
#pragma unroll
    for (int nf = 0; nf < 4; nf++) {
        int n = wave * 64 + nf * 16 + lm;
#pragma unroll
        for (int rg = 0; rg < 4; rg++)
            A_lds[q * 4 + rg][n] = f2bf(acc[nf][rg] * linv[rg]);
    }
    __syncthreads();

    // out-projection: [16][256] @ Wo + bo, each wave 64 n
    f32x4 oacc[4];
#pragma unroll
    for (int nf = 0; nf < 4; nf++) oacc[nf] = (f32x4)(0.f);
    for (int k0 = 0; k0 < 256; k0 += 32) {
        bf16x8 afr = *reinterpret_cast<const bf16x8*>(&A_lds[lm][k0 + q * 8]);
#pragma unroll
        for (int nf = 0; nf < 4; nf++) {
            int n = wave * 64 + nf * 16 + lm;
            bf16x8 bfrW = *reinterpret_cast<const bf16x8*>(
                Wot + (size_t)n * 256 + k0 + q * 8);
            oacc[nf] = __builtin_amdgcn_mfma_f32_16x16x32_bf16(
                afr, bfrW, oacc[nf], 0, 0, 0);
        }
    }
#pragma unroll
    for (int nf = 0; nf < 4; nf++) {
        int n = wave * 64 + nf * 16 + lm;
        float bias_n = bo[n];
#pragma unroll
        for (int rg = 0; rg < 4; rg++)
            out[((size_t)(b * L + i0 + q * 4 + rg)) * 256 + n] = oacc[nf][rg] + bias_n;
    }
}

extern "C" void kernel_launch(void* const* d_in, const int* in_sizes, int n_in,
                              void* d_out, int out_size, void* d_ws, size_t ws_size,
                              hipStream_t stream) {
    (void)in_sizes; (void)n_in; (void)out_size; (void)ws_size;
    const float* atten = (const float*)d_in[0];
    const float* value = (const float*)d_in[1];
    const float* mask  = (const float*)d_in[2];
    const int*   pad   = (const int*)d_in[3];
    const float* Wv    = (const float*)d_in[4];
    const float* bv    = (const float*)d_in[5];
    const float* Wo    = (const float*)d_in[6];
    const float* bo    = (const float*)d_in[7];
    float* out = (float*)d_out;

    char* ws = (char*)d_ws;
    unsigned short* Vt  = (unsigned short*)(ws);              // 4 MB  bf16 [B][D][L]
    unsigned short* Wot = (unsigned short*)(ws + 4194304);    // 128 KB

    prep_kernel<<<dim3(256, 4), 256, 0, stream>>>(value, Wv, bv, Wo, Vt, Wot);
    attn_kernel<<<512, 256, 0, stream>>>(atten, mask, pad, Vt, Wot, bo, out);
}